// Round 9
// baseline (268.603 us; speedup 1.0000x reference)
//
#include <hip/hip_runtime.h>

// Problem constants
#define BB 4
#define SS 2048
#define DM 256
#define NH 4
#define DH 64
#define NROW (BB*SS)              // 8192
#define NE   (3*DM)               // 768
#define BH   (BB*NH)              // 16
#define HEAD_ELEMS (BH*SS*DH)     // 2097152 per tensor
#define NQROWS (BH*SS)            // 32768

typedef _Float16 half_t;
typedef __attribute__((ext_vector_type(8))) _Float16 half8;
typedef __attribute__((ext_vector_type(4))) _Float16 half4;
typedef __attribute__((ext_vector_type(4))) float floatx4;

#define KPAD 72                   // attn LDS stride in halfs (144 B)
#define XPAD 264                  // qkv x-strip stride in halfs (256+8)
// q pre-scale: 1/sqrt(64) * log2(e)  -> softmax runs in exp2 domain
#define QSCALE 0.1803368801111120f

// ---------------------------------------------------------------------------
// prep: one-shot conversion  x -> (x_hi, x_lo) fp16,  W -> fp16.
// ---------------------------------------------------------------------------
__global__ __launch_bounds__(256) void prep(const float* __restrict__ x,
                                            const float* __restrict__ W,
                                            half_t* __restrict__ xh,
                                            half_t* __restrict__ xl,
                                            half_t* __restrict__ wh) {
    int gtid = blockIdx.x * 256 + threadIdx.x;    // 0..524287
    {
        int i = gtid * 4;
        float4 v = *(const float4*)&x[i];
        half4 h, l;
        h.x = (half_t)v.x; l.x = (half_t)(v.x - (float)h.x);
        h.y = (half_t)v.y; l.y = (half_t)(v.y - (float)h.y);
        h.z = (half_t)v.z; l.z = (half_t)(v.z - (float)h.z);
        h.w = (half_t)v.w; l.w = (half_t)(v.w - (float)h.w);
        *(half4*)&xh[i] = h;
        *(half4*)&xl[i] = l;
    }
    if (gtid < NE * DM / 4) {
        int i = gtid * 4;
        float4 v = *(const float4*)&W[i];
        half4 h;
        h.x = (half_t)v.x; h.y = (half_t)v.y;
        h.z = (half_t)v.z; h.w = (half_t)v.w;
        *(half4*)&wh[i] = h;
    }
}

// ---------------------------------------------------------------------------
// QKV projection v2: barrier-free K-loop.
// Block = 256 thr / 4 waves, 64 rows x 64 features. The FULL 64x256 x-strip
// (hi+lo, 64 KB) is staged in LDS once (one barrier). W B-frags are read
// directly from global (384 KB total -> L2-resident; no intra-block reuse so
// the loads pipeline). 8 K32-chunks of pure MFMA follow with no syncs.
// ---------------------------------------------------------------------------
__global__ __launch_bounds__(256) void qkv_proj(const half_t* __restrict__ xh,
                                                const half_t* __restrict__ xl,
                                                const half_t* __restrict__ whg,
                                                const float* __restrict__ bias,
                                                half_t* __restrict__ qh,
                                                half_t* __restrict__ kh,
                                                half_t* __restrict__ vt) {
    __shared__ __align__(16) half_t Xh2[64 * XPAD];   // x hi, [row][k]
    __shared__ __align__(16) half_t Xl2[64 * XPAD];   // x lo, [row][k]

    const int rb   = blockIdx.x * 64;
    const int nb   = blockIdx.y * 64;
    const int tid  = threadIdx.x;
    const int wid  = tid >> 6;
    const int lane = tid & 63;
    const int quad = lane >> 4;
    const int col  = lane & 15;

    // Stage the whole x strip (hi+lo): 2048 half8 per tensor, 8 per thread.
    #pragma unroll
    for (int i = 0; i < 8; ++i) {
        int gi = tid + 256 * i;        // 0..2047
        int r  = gi >> 5;              // 0..63
        int c8 = (gi & 31) * 8;        // 0..248
        *(half8*)&Xh2[r * XPAD + c8] = *(const half8*)&xh[(size_t)(rb + r) * DM + c8];
        *(half8*)&Xl2[r * XPAD + c8] = *(const half8*)&xl[(size_t)(rb + r) * DM + c8];
    }
    __syncthreads();

    floatx4 acc[4];
    #pragma unroll
    for (int t = 0; t < 4; ++t) acc[t] = (floatx4){0.f, 0.f, 0.f, 0.f};

    const int arow = (wid * 16 + col) * XPAD + quad * 8;
    #pragma unroll
    for (int k0 = 0; k0 < DM; k0 += 32) {
        half8 bw[4];
        #pragma unroll
        for (int t = 0; t < 4; ++t)
            bw[t] = *(const half8*)&whg[(size_t)(nb + t * 16 + col) * DM + k0 + quad * 8];
        half8 ah = *(const half8*)&Xh2[arow + k0];
        half8 al = *(const half8*)&Xl2[arow + k0];
        #pragma unroll
        for (int t = 0; t < 4; ++t) {
            acc[t] = __builtin_amdgcn_mfma_f32_16x16x32_f16(ah, bw[t], acc[t], 0, 0, 0);
            acc[t] = __builtin_amdgcn_mfma_f32_16x16x32_f16(al, bw[t], acc[t], 0, 0, 0);
        }
    }

    const int part = nb >> 8;           // block-uniform: 0=q 1=k 2=v
    const int mloc = wid * 16 + quad * 4;
    if (part != 2) {
        #pragma unroll
        for (int t = 0; t < 4; ++t) {
            int e    = nb + t * 16 + col;
            float be = bias[e];
            int dm   = e & 255;
            int h    = dm >> 6;
            int dh   = dm & 63;
            #pragma unroll
            for (int r = 0; r < 4; ++r) {
                int row = rb + mloc + r;
                int b   = row >> 11;
                int s   = row & 2047;
                int bh_ = b * NH + h;
                float val = acc[t][r] + be;
                if (part == 0) {
                    qh[((size_t)bh_ * SS + s) * DH + dh] = (half_t)(val * QSCALE);
                } else {
                    kh[((size_t)bh_ * SS + s) * DH + dh] = (half_t)val;
                }
            }
        }
    } else {
        // v: transpose 64(feat) x 64(row) tile through LDS (reuse Xh2 head)
        __syncthreads();    // all waves done reading Xh2 for MFMA
        #pragma unroll
        for (int t = 0; t < 4; ++t) {
            int e    = nb + t * 16 + col;
            float be = bias[e];
            #pragma unroll
            for (int r = 0; r < 4; ++r)
                Xh2[(t * 16 + col) * KPAD + mloc + r] = (half_t)(acc[t][r] + be);
        }
        __syncthreads();
        const int b   = rb >> 11;
        const int s0  = rb & 2047;
        const int h   = (nb >> 6) & 3;
        const int bh_ = b * NH + h;
        #pragma unroll
        for (int i = 0; i < 2; ++i) {
            int idx = tid + 256 * i;   // 0..511
            int rr  = idx >> 3;        // feat 0..63
            int cc8 = (idx & 7) * 8;   // row chunk
            *(half8*)&vt[((size_t)bh_ * DH + rr) * SS + s0 + cc8] =
                *(const half8*)&Xh2[rr * KPAD + cc8];
        }
    }
}

// ---------------------------------------------------------------------------
// Flash attention (round-5 proven core), fp16 MFMA, S^T trick, 32 q/wave,
// 2-wave blocks, single-buffer LDS + 2 barriers + 1-tile register prefetch.
// Split-K factor = gridDim.z (2 or 4, chosen by ws_size at launch).
// Writes normalized partial O (fp16) + m,l stats per kz slice.
// ---------------------------------------------------------------------------
__global__ __launch_bounds__(128, 4) void attn(const half_t* __restrict__ qh,
                                               const half_t* __restrict__ kh,
                                               const half_t* __restrict__ vt,
                                               half_t* __restrict__ pO,
                                               float* __restrict__ mst,
                                               float* __restrict__ lst) {
    __shared__ __align__(16) half_t Ks[64 * KPAD];    // [kr][d]
    __shared__ __align__(16) half_t Vts[64 * KPAD];   // [d][kr]

    const int q0   = blockIdx.x * 64;
    const int bh   = blockIdx.y;
    const int kz   = blockIdx.z;
    const size_t base = (size_t)bh * SS * DH;
    const int tid  = threadIdx.x;
    const int wid  = tid >> 6;    // 0..1
    const int lane = tid & 63;
    const int quad = lane >> 4;
    const int col  = lane & 15;
    const int span  = SS / gridDim.z;
    const int ktBeg = kz * span;
    const int ktEnd = ktBeg + span;

    int srr[4], scc[4];
    #pragma unroll
    for (int i = 0; i < 4; ++i) {
        int gi = tid + 128 * i;    // 0..511
        srr[i] = gi >> 3;          // 0..63
        scc[i] = (gi & 7) * 8;     // 0..56
    }

    // Q B-frags: 2 strips of 16 q rows (pre-scaled by QSCALE)
    half8 bq[2][2];
    #pragma unroll
    for (int st = 0; st < 2; ++st) {
        int s = q0 + wid * 32 + st * 16 + col;
        bq[st][0] = *(const half8*)&qh[base + (size_t)s * DH + quad * 8];
        bq[st][1] = *(const half8*)&qh[base + (size_t)s * DH + 32 + quad * 8];
    }

    // Preload tile ktBeg into cur regs
    half8 ck[4], cv[4];
    #pragma unroll
    for (int i = 0; i < 4; ++i) {
        ck[i] = *(const half8*)&kh[base + (size_t)(ktBeg + srr[i]) * DH + scc[i]];
        cv[i] = *(const half8*)&vt[base + (size_t)srr[i] * SS + ktBeg + scc[i]];
    }

    float m_i[2] = {-3.0e38f, -3.0e38f};
    float l_i[2] = {0.f, 0.f};
    floatx4 o[2][4];
    #pragma unroll
    for (int st = 0; st < 2; ++st)
        #pragma unroll
        for (int dt = 0; dt < 4; ++dt) o[st][dt] = (floatx4){0.f, 0.f, 0.f, 0.f};

    for (int kt = ktBeg; kt < ktEnd; kt += 64) {
        __syncthreads();   // previous compute done reading LDS
        #pragma unroll
        for (int i = 0; i < 4; ++i) {
            *(half8*)&Ks[srr[i] * KPAD + scc[i]]  = ck[i];
            *(half8*)&Vts[srr[i] * KPAD + scc[i]] = cv[i];
        }
        __syncthreads();   // tiles visible to both waves

        // Prefetch next tile (in flight across the whole compute phase)
        const int ktn = kt + 64;
        if (ktn < ktEnd) {
            #pragma unroll
            for (int i = 0; i < 4; ++i) {
                ck[i] = *(const half8*)&kh[base + (size_t)(ktn + srr[i]) * DH + scc[i]];
                cv[i] = *(const half8*)&vt[base + (size_t)srr[i] * SS + ktn + scc[i]];
            }
        }

        // S^T = K · Q^T (ak frags shared by both strips)
        floatx4 sc[2][4];
        #pragma unroll
        for (int t = 0; t < 4; ++t) {
            half8 ak0 = *(const half8*)&Ks[(t * 16 + col) * KPAD + quad * 8];
            half8 ak1 = *(const half8*)&Ks[(t * 16 + col) * KPAD + 32 + quad * 8];
            #pragma unroll
            for (int st = 0; st < 2; ++st) {
                floatx4 c = (floatx4){0.f, 0.f, 0.f, 0.f};
                c = __builtin_amdgcn_mfma_f32_16x16x32_f16(ak0, bq[st][0], c, 0, 0, 0);
                c = __builtin_amdgcn_mfma_f32_16x16x32_f16(ak1, bq[st][1], c, 0, 0, 0);
                sc[st][t] = c;
            }
        }

        // Online softmax per strip (exp2 domain)
        half4 pa[2][4];
        #pragma unroll
        for (int st = 0; st < 2; ++st) {
            float mloc = -3.0e38f;
            #pragma unroll
            for (int t = 0; t < 4; ++t)
                #pragma unroll
                for (int r = 0; r < 4; ++r)
                    mloc = fmaxf(mloc, sc[st][t][r]);
            mloc = fmaxf(mloc, __shfl_xor(mloc, 16));
            mloc = fmaxf(mloc, __shfl_xor(mloc, 32));
            float m_new = fmaxf(m_i[st], mloc);
            float alpha = exp2f(m_i[st] - m_new);
            m_i[st] = m_new;

            float rsum = 0.f;
            #pragma unroll
            for (int t = 0; t < 4; ++t) {
                float p0 = exp2f(sc[st][t][0] - m_new);
                float p1 = exp2f(sc[st][t][1] - m_new);
                float p2 = exp2f(sc[st][t][2] - m_new);
                float p3 = exp2f(sc[st][t][3] - m_new);
                rsum += p0 + p1 + p2 + p3;
                pa[st][t] = (half4){(half_t)p0, (half_t)p1, (half_t)p2, (half_t)p3};
            }
            rsum += __shfl_xor(rsum, 16);
            rsum += __shfl_xor(rsum, 32);
            l_i[st] = l_i[st] * alpha + rsum;

            float ar[4];
            #pragma unroll
            for (int i = 0; i < 4; ++i) ar[i] = __shfl(alpha, quad * 4 + i);
            #pragma unroll
            for (int dt = 0; dt < 4; ++dt)
                #pragma unroll
                for (int i = 0; i < 4; ++i)
                    o[st][dt][i] *= ar[i];
        }

        // O += P · V  (bv frags shared by both strips)
        #pragma unroll
        for (int t = 0; t < 4; ++t) {
            #pragma unroll
            for (int dt = 0; dt < 4; ++dt) {
                half4 bv = *(const half4*)&Vts[(dt * 16 + col) * KPAD + t * 16 + quad * 4];
                #pragma unroll
                for (int st = 0; st < 2; ++st)
                    o[st][dt] = __builtin_amdgcn_mfma_f32_16x16x16f16(pa[st][t], bv, o[st][dt], 0, 0, 0);
            }
        }
    }

    // Epilogue: normalized partial O (fp16) + stats
    const size_t pbase = (size_t)kz * HEAD_ELEMS + base;
    #pragma unroll
    for (int st = 0; st < 2; ++st) {
        float inv = 1.0f / l_i[st];
        float ir[4];
        #pragma unroll
        for (int i = 0; i < 4; ++i) ir[i] = __shfl(inv, quad * 4 + i);
        #pragma unroll
        for (int dt = 0; dt < 4; ++dt)
            #pragma unroll
            for (int i = 0; i < 4; ++i) {
                int row = q0 + wid * 32 + st * 16 + quad * 4 + i;
                pO[pbase + (size_t)row * DH + dt * 16 + col] = (half_t)(o[st][dt][i] * ir[i]);
            }
        if (quad == 0) {
            int row = q0 + wid * 32 + st * 16 + col;
            int idx = kz * NQROWS + bh * SS + row;
            mst[idx] = m_i[st];
            lst[idx] = l_i[st];
        }
    }
}

// ---------------------------------------------------------------------------
// merge: combine nsplit kz partials (normalized O, exp2-domain m).
// ---------------------------------------------------------------------------
__global__ __launch_bounds__(256) void merge(const half_t* __restrict__ pO,
                                             const float* __restrict__ mst,
                                             const float* __restrict__ lst,
                                             float* __restrict__ out,
                                             int nsplit) {
    int gid = blockIdx.x * 256 + threadIdx.x;   // 0..262143
    int row = gid >> 3;                         // bh*SS + s
    int dc  = (gid & 7) * 8;
    float M = -3.0e38f;
    for (int j = 0; j < nsplit; ++j) M = fmaxf(M, mst[j * NQROWS + row]);
    float w[4];
    float wsum = 0.f;
    for (int j = 0; j < nsplit; ++j) {
        w[j] = lst[j * NQROWS + row] * exp2f(mst[j * NQROWS + row] - M);
        wsum += w[j];
    }
    float inv = 1.0f / wsum;
    float acc[8] = {0.f, 0.f, 0.f, 0.f, 0.f, 0.f, 0.f, 0.f};
    for (int j = 0; j < nsplit; ++j) {
        half8 oj = *(const half8*)&pO[(size_t)j * HEAD_ELEMS + (size_t)row * DH + dc];
        float wj = w[j];
        #pragma unroll
        for (int e = 0; e < 8; ++e) acc[e] += wj * (float)oj[e];
    }
    float4 r0, r1;
    r0.x = acc[0] * inv; r0.y = acc[1] * inv; r0.z = acc[2] * inv; r0.w = acc[3] * inv;
    r1.x = acc[4] * inv; r1.y = acc[5] * inv; r1.z = acc[6] * inv; r1.w = acc[7] * inv;
    *(float4*)&out[(size_t)row * DH + dc]     = r0;
    *(float4*)&out[(size_t)row * DH + dc + 4] = r1;
}

extern "C" void kernel_launch(void* const* d_in, const int* in_sizes, int n_in,
                              void* d_out, int out_size, void* d_ws, size_t ws_size,
                              hipStream_t stream) {
    const float* x  = (const float*)d_in[0];   // [4,2048,256]
    const float* Wq = (const float*)d_in[1];   // [768,256]
    const float* bq = (const float*)d_in[2];   // [768]
    float* out = (float*)d_out;                // [4,4,2048,64]

    // ws layout (bytes):
    //   qh 0 | kh 4M | vt 8M | xh 12M | xl 16M | whp 20.97M (prep/qkv only)
    //   pO starts at 12,582,912 (aliases xh/xl/whp — all dead once qkv ends):
    //     nsplit*HEAD_ELEMS*2 bytes; stats follow pO.
    half_t* qh  = (half_t*)d_ws;
    half_t* kh  = qh + (size_t)HEAD_ELEMS;
    half_t* vt  = kh + (size_t)HEAD_ELEMS;
    half_t* xh  = vt + (size_t)HEAD_ELEMS;
    half_t* xl  = xh + (size_t)HEAD_ELEMS;
    half_t* whp = xl + (size_t)HEAD_ELEMS;             // 196608 halfs
    half_t* pO  = xh;                                  // alias

    // split-K 4 needs 12.58M + 16.78M + 1.05M ≈ 30.4 MB of ws
    const int nsplit = (ws_size >= 31000000u) ? 4 : 2;
    float* mst = (float*)((char*)d_ws + 12582912 + (size_t)nsplit * HEAD_ELEMS * 2);
    float* lst = mst + (size_t)nsplit * NQROWS;

    prep<<<2048, 256, 0, stream>>>(x, Wq, xh, xl, whp);
    qkv_proj<<<dim3(NROW / 64, NE / 64), 256, 0, stream>>>(xh, xl, whp, bq, qh, kh, vt);
    attn<<<dim3(SS / 64, BH, nsplit), 128, 0, stream>>>(qh, kh, vt, pO, mst, lst);
    merge<<<1024, 256, 0, stream>>>(pO, mst, lst, out, nsplit);
}

// Round 10
// 136.452 us; speedup vs baseline: 1.9685x; 1.9685x over previous
//
#include <hip/hip_runtime.h>

// Problem constants
#define BB 4
#define SS 2048
#define DM 256
#define NH 4
#define DH 64
#define NROW (BB*SS)              // 8192
#define NE   (3*DM)               // 768
#define BH   (BB*NH)              // 16
#define HEAD_ELEMS (BH*SS*DH)     // 2097152 per tensor
#define NQROWS (BH*SS)            // 32768

typedef _Float16 half_t;
typedef __attribute__((ext_vector_type(8))) _Float16 half8;
typedef __attribute__((ext_vector_type(4))) _Float16 half4;
typedef __attribute__((ext_vector_type(4))) float floatx4;

#define KPAD 72                   // LDS stride in halfs (144 B, 16B-aligned rows)
// q pre-scale: 1/sqrt(64) * log2(e)  -> softmax runs in exp2 domain
#define QSCALE 0.1803368801111120f

// ---------------------------------------------------------------------------
// prep: one-shot conversion  x -> (x_hi, x_lo) fp16,  W -> fp16.
// ---------------------------------------------------------------------------
__global__ __launch_bounds__(256) void prep(const float* __restrict__ x,
                                            const float* __restrict__ W,
                                            half_t* __restrict__ xh,
                                            half_t* __restrict__ xl,
                                            half_t* __restrict__ wh) {
    int gtid = blockIdx.x * 256 + threadIdx.x;    // 0..524287
    {
        int i = gtid * 4;
        float4 v = *(const float4*)&x[i];
        half4 h, l;
        h.x = (half_t)v.x; l.x = (half_t)(v.x - (float)h.x);
        h.y = (half_t)v.y; l.y = (half_t)(v.y - (float)h.y);
        h.z = (half_t)v.z; l.z = (half_t)(v.z - (float)h.z);
        h.w = (half_t)v.w; l.w = (half_t)(v.w - (float)h.w);
        *(half4*)&xh[i] = h;
        *(half4*)&xl[i] = l;
    }
    if (gtid < NE * DM / 4) {
        int i = gtid * 4;
        float4 v = *(const float4*)&W[i];
        half4 h;
        h.x = (half_t)v.x; h.y = (half_t)v.y;
        h.z = (half_t)v.z; h.w = (half_t)v.w;
        *(half4*)&wh[i] = h;
    }
}

// ---------------------------------------------------------------------------
// QKV projection (round-5 proven structure), fp16 MFMA, hi/lo-split x.
// q is pre-scaled by QSCALE (softmax in exp2 domain).
// ---------------------------------------------------------------------------
__global__ __launch_bounds__(256) void qkv_proj(const half_t* __restrict__ xh,
                                                const half_t* __restrict__ xl,
                                                const half_t* __restrict__ whg,
                                                const float* __restrict__ bias,
                                                half_t* __restrict__ qh,
                                                half_t* __restrict__ kh,
                                                half_t* __restrict__ vt) {
    __shared__ __align__(16) half_t Xh[64 * KPAD];
    __shared__ __align__(16) half_t Xl[64 * KPAD];
    __shared__ __align__(16) half_t Wh[64 * KPAD];

    const int rb   = blockIdx.x * 64;
    const int nb   = blockIdx.y * 64;
    const int tid  = threadIdx.x;
    const int wid  = tid >> 6;
    const int lane = tid & 63;
    const int quad = lane >> 4;
    const int col  = lane & 15;

    floatx4 acc[4];
    #pragma unroll
    for (int t = 0; t < 4; ++t) acc[t] = (floatx4){0.f, 0.f, 0.f, 0.f};

    for (int k0 = 0; k0 < DM; k0 += 64) {
        __syncthreads();
        #pragma unroll
        for (int i = 0; i < 2; ++i) {
            int gi = tid + 256 * i;        // 0..511
            int r  = gi >> 3;              // 0..63
            int c8 = (gi & 7) * 8;         // 0..56
            *(half8*)&Xh[r * KPAD + c8] = *(const half8*)&xh[(size_t)(rb + r) * DM + k0 + c8];
            *(half8*)&Xl[r * KPAD + c8] = *(const half8*)&xl[(size_t)(rb + r) * DM + k0 + c8];
            *(half8*)&Wh[r * KPAD + c8] = *(const half8*)&whg[(size_t)(nb + r) * DM + k0 + c8];
        }
        __syncthreads();

        half8 ah0 = *(const half8*)&Xh[(wid * 16 + col) * KPAD + quad * 8];
        half8 ah1 = *(const half8*)&Xh[(wid * 16 + col) * KPAD + 32 + quad * 8];
        half8 al0 = *(const half8*)&Xl[(wid * 16 + col) * KPAD + quad * 8];
        half8 al1 = *(const half8*)&Xl[(wid * 16 + col) * KPAD + 32 + quad * 8];

        #pragma unroll
        for (int t = 0; t < 4; ++t) {
            half8 bh0 = *(const half8*)&Wh[(t * 16 + col) * KPAD + quad * 8];
            half8 bh1 = *(const half8*)&Wh[(t * 16 + col) * KPAD + 32 + quad * 8];
            acc[t] = __builtin_amdgcn_mfma_f32_16x16x32_f16(ah0, bh0, acc[t], 0, 0, 0);
            acc[t] = __builtin_amdgcn_mfma_f32_16x16x32_f16(ah1, bh1, acc[t], 0, 0, 0);
            acc[t] = __builtin_amdgcn_mfma_f32_16x16x32_f16(al0, bh0, acc[t], 0, 0, 0);
            acc[t] = __builtin_amdgcn_mfma_f32_16x16x32_f16(al1, bh1, acc[t], 0, 0, 0);
        }
    }

    const int part = nb >> 8;           // block-uniform: 0=q 1=k 2=v
    const int mloc = wid * 16 + quad * 4;
    if (part != 2) {
        #pragma unroll
        for (int t = 0; t < 4; ++t) {
            int e    = nb + t * 16 + col;
            float be = bias[e];
            int dm   = e & 255;
            int h    = dm >> 6;
            int dh   = dm & 63;
            #pragma unroll
            for (int r = 0; r < 4; ++r) {
                int row = rb + mloc + r;
                int b   = row >> 11;
                int s   = row & 2047;
                int bh_ = b * NH + h;
                float val = acc[t][r] + be;
                if (part == 0) {
                    qh[((size_t)bh_ * SS + s) * DH + dh] = (half_t)(val * QSCALE);
                } else {
                    kh[((size_t)bh_ * SS + s) * DH + dh] = (half_t)val;
                }
            }
        }
    } else {
        __syncthreads();
        #pragma unroll
        for (int t = 0; t < 4; ++t) {
            int e    = nb + t * 16 + col;
            float be = bias[e];
            #pragma unroll
            for (int r = 0; r < 4; ++r)
                Xh[(t * 16 + col) * KPAD + mloc + r] = (half_t)(acc[t][r] + be);
        }
        __syncthreads();
        const int b   = rb >> 11;
        const int s0  = rb & 2047;
        const int h   = (nb >> 6) & 3;
        const int bh_ = b * NH + h;
        #pragma unroll
        for (int i = 0; i < 2; ++i) {
            int idx = tid + 256 * i;
            int rr  = idx >> 3;
            int cc8 = (idx & 7) * 8;
            *(half8*)&vt[((size_t)bh_ * DH + rr) * SS + s0 + cc8] =
                *(const half8*)&Xh[rr * KPAD + cc8];
        }
    }
}

// ---------------------------------------------------------------------------
// Flash attention (round-5 proven core), fp16 MFMA, S^T trick, 32 q/wave,
// 2-wave blocks, single-buffer LDS + 2 barriers + 1-tile register prefetch.
// Split-K factor = gridDim.z (4 when ws permits, else 2).
// __launch_bounds__(128,2): the r5/r8-proven codegen (VGPR ~112, NO spill).
// ---------------------------------------------------------------------------
__global__ __launch_bounds__(128, 2) void attn(const half_t* __restrict__ qh,
                                               const half_t* __restrict__ kh,
                                               const half_t* __restrict__ vt,
                                               half_t* __restrict__ pO,
                                               float* __restrict__ mst,
                                               float* __restrict__ lst) {
    __shared__ __align__(16) half_t Ks[64 * KPAD];    // [kr][d]
    __shared__ __align__(16) half_t Vts[64 * KPAD];   // [d][kr]

    const int q0   = blockIdx.x * 64;
    const int bh   = blockIdx.y;
    const int kz   = blockIdx.z;
    const size_t base = (size_t)bh * SS * DH;
    const int tid  = threadIdx.x;
    const int wid  = tid >> 6;    // 0..1
    const int lane = tid & 63;
    const int quad = lane >> 4;
    const int col  = lane & 15;
    const int span  = SS / gridDim.z;
    const int ktBeg = kz * span;
    const int ktEnd = ktBeg + span;

    int srr[4], scc[4];
    #pragma unroll
    for (int i = 0; i < 4; ++i) {
        int gi = tid + 128 * i;    // 0..511
        srr[i] = gi >> 3;          // 0..63
        scc[i] = (gi & 7) * 8;     // 0..56
    }

    // Q B-frags: 2 strips of 16 q rows (pre-scaled by QSCALE)
    half8 bq[2][2];
    #pragma unroll
    for (int st = 0; st < 2; ++st) {
        int s = q0 + wid * 32 + st * 16 + col;
        bq[st][0] = *(const half8*)&qh[base + (size_t)s * DH + quad * 8];
        bq[st][1] = *(const half8*)&qh[base + (size_t)s * DH + 32 + quad * 8];
    }

    // Preload tile ktBeg into cur regs
    half8 ck[4], cv[4];
    #pragma unroll
    for (int i = 0; i < 4; ++i) {
        ck[i] = *(const half8*)&kh[base + (size_t)(ktBeg + srr[i]) * DH + scc[i]];
        cv[i] = *(const half8*)&vt[base + (size_t)srr[i] * SS + ktBeg + scc[i]];
    }

    float m_i[2] = {-3.0e38f, -3.0e38f};
    float l_i[2] = {0.f, 0.f};
    floatx4 o[2][4];
    #pragma unroll
    for (int st = 0; st < 2; ++st)
        #pragma unroll
        for (int dt = 0; dt < 4; ++dt) o[st][dt] = (floatx4){0.f, 0.f, 0.f, 0.f};

    for (int kt = ktBeg; kt < ktEnd; kt += 64) {
        __syncthreads();   // previous compute done reading LDS
        #pragma unroll
        for (int i = 0; i < 4; ++i) {
            *(half8*)&Ks[srr[i] * KPAD + scc[i]]  = ck[i];
            *(half8*)&Vts[srr[i] * KPAD + scc[i]] = cv[i];
        }
        __syncthreads();   // tiles visible to both waves

        // Prefetch next tile (in flight across the whole compute phase)
        const int ktn = kt + 64;
        if (ktn < ktEnd) {
            #pragma unroll
            for (int i = 0; i < 4; ++i) {
                ck[i] = *(const half8*)&kh[base + (size_t)(ktn + srr[i]) * DH + scc[i]];
                cv[i] = *(const half8*)&vt[base + (size_t)srr[i] * SS + ktn + scc[i]];
            }
        }

        // S^T = K · Q^T (ak frags shared by both strips)
        floatx4 sc[2][4];
        #pragma unroll
        for (int t = 0; t < 4; ++t) {
            half8 ak0 = *(const half8*)&Ks[(t * 16 + col) * KPAD + quad * 8];
            half8 ak1 = *(const half8*)&Ks[(t * 16 + col) * KPAD + 32 + quad * 8];
            #pragma unroll
            for (int st = 0; st < 2; ++st) {
                floatx4 c = (floatx4){0.f, 0.f, 0.f, 0.f};
                c = __builtin_amdgcn_mfma_f32_16x16x32_f16(ak0, bq[st][0], c, 0, 0, 0);
                c = __builtin_amdgcn_mfma_f32_16x16x32_f16(ak1, bq[st][1], c, 0, 0, 0);
                sc[st][t] = c;
            }
        }

        // Online softmax per strip (exp2 domain)
        half4 pa[2][4];
        #pragma unroll
        for (int st = 0; st < 2; ++st) {
            float mloc = -3.0e38f;
            #pragma unroll
            for (int t = 0; t < 4; ++t)
                #pragma unroll
                for (int r = 0; r < 4; ++r)
                    mloc = fmaxf(mloc, sc[st][t][r]);
            mloc = fmaxf(mloc, __shfl_xor(mloc, 16));
            mloc = fmaxf(mloc, __shfl_xor(mloc, 32));
            float m_new = fmaxf(m_i[st], mloc);
            float alpha = exp2f(m_i[st] - m_new);
            m_i[st] = m_new;

            float rsum = 0.f;
            #pragma unroll
            for (int t = 0; t < 4; ++t) {
                float p0 = exp2f(sc[st][t][0] - m_new);
                float p1 = exp2f(sc[st][t][1] - m_new);
                float p2 = exp2f(sc[st][t][2] - m_new);
                float p3 = exp2f(sc[st][t][3] - m_new);
                rsum += p0 + p1 + p2 + p3;
                pa[st][t] = (half4){(half_t)p0, (half_t)p1, (half_t)p2, (half_t)p3};
            }
            rsum += __shfl_xor(rsum, 16);
            rsum += __shfl_xor(rsum, 32);
            l_i[st] = l_i[st] * alpha + rsum;

            float ar[4];
            #pragma unroll
            for (int i = 0; i < 4; ++i) ar[i] = __shfl(alpha, quad * 4 + i);
            #pragma unroll
            for (int dt = 0; dt < 4; ++dt)
                #pragma unroll
                for (int i = 0; i < 4; ++i)
                    o[st][dt][i] *= ar[i];
        }

        // O += P · V  (bv frags shared by both strips)
        #pragma unroll
        for (int t = 0; t < 4; ++t) {
            #pragma unroll
            for (int dt = 0; dt < 4; ++dt) {
                half4 bv = *(const half4*)&Vts[(dt * 16 + col) * KPAD + t * 16 + quad * 4];
                #pragma unroll
                for (int st = 0; st < 2; ++st)
                    o[st][dt] = __builtin_amdgcn_mfma_f32_16x16x16f16(pa[st][t], bv, o[st][dt], 0, 0, 0);
            }
        }
    }

    // Epilogue: normalized partial O (fp16) + stats
    const size_t pbase = (size_t)kz * HEAD_ELEMS + base;
    #pragma unroll
    for (int st = 0; st < 2; ++st) {
        float inv = 1.0f / l_i[st];
        float ir[4];
        #pragma unroll
        for (int i = 0; i < 4; ++i) ir[i] = __shfl(inv, quad * 4 + i);
        #pragma unroll
        for (int dt = 0; dt < 4; ++dt)
            #pragma unroll
            for (int i = 0; i < 4; ++i) {
                int row = q0 + wid * 32 + st * 16 + quad * 4 + i;
                pO[pbase + (size_t)row * DH + dt * 16 + col] = (half_t)(o[st][dt][i] * ir[i]);
            }
        if (quad == 0) {
            int row = q0 + wid * 32 + st * 16 + col;
            int idx = kz * NQROWS + bh * SS + row;
            mst[idx] = m_i[st];
            lst[idx] = l_i[st];
        }
    }
}

// ---------------------------------------------------------------------------
// merge: combine nsplit kz partials (normalized O, exp2-domain m).
// Numerics proven in round 9 (split-4 passed with absmax 9.8e-4).
// ---------------------------------------------------------------------------
__global__ __launch_bounds__(256) void merge(const half_t* __restrict__ pO,
                                             const float* __restrict__ mst,
                                             const float* __restrict__ lst,
                                             float* __restrict__ out,
                                             int nsplit) {
    int gid = blockIdx.x * 256 + threadIdx.x;   // 0..262143
    int row = gid >> 3;                         // bh*SS + s
    int dc  = (gid & 7) * 8;
    float M = -3.0e38f;
    for (int j = 0; j < nsplit; ++j) M = fmaxf(M, mst[j * NQROWS + row]);
    float w[4];
    float wsum = 0.f;
    for (int j = 0; j < nsplit; ++j) {
        w[j] = lst[j * NQROWS + row] * exp2f(mst[j * NQROWS + row] - M);
        wsum += w[j];
    }
    float inv = 1.0f / wsum;
    float acc[8] = {0.f, 0.f, 0.f, 0.f, 0.f, 0.f, 0.f, 0.f};
    for (int j = 0; j < nsplit; ++j) {
        half8 oj = *(const half8*)&pO[(size_t)j * HEAD_ELEMS + (size_t)row * DH + dc];
        float wj = w[j];
        #pragma unroll
        for (int e = 0; e < 8; ++e) acc[e] += wj * (float)oj[e];
    }
    float4 r0, r1;
    r0.x = acc[0] * inv; r0.y = acc[1] * inv; r0.z = acc[2] * inv; r0.w = acc[3] * inv;
    r1.x = acc[4] * inv; r1.y = acc[5] * inv; r1.z = acc[6] * inv; r1.w = acc[7] * inv;
    *(float4*)&out[(size_t)row * DH + dc]     = r0;
    *(float4*)&out[(size_t)row * DH + dc + 4] = r1;
}

extern "C" void kernel_launch(void* const* d_in, const int* in_sizes, int n_in,
                              void* d_out, int out_size, void* d_ws, size_t ws_size,
                              hipStream_t stream) {
    const float* x  = (const float*)d_in[0];   // [4,2048,256]
    const float* Wq = (const float*)d_in[1];   // [768,256]
    const float* bq = (const float*)d_in[2];   // [768]
    float* out = (float*)d_out;                // [4,4,2048,64]

    // ws layout (bytes):
    //   qh 0 | kh 4M | vt 8M | xh 12M | xl 16M | whp 20.97M (prep/qkv only)
    //   pO starts at 12,582,912 (aliases xh/xl/whp — dead once qkv ends):
    //     nsplit*HEAD_ELEMS*2 bytes; mst/lst follow pO.
    half_t* qh  = (half_t*)d_ws;
    half_t* kh  = qh + (size_t)HEAD_ELEMS;
    half_t* vt  = kh + (size_t)HEAD_ELEMS;
    half_t* xh  = vt + (size_t)HEAD_ELEMS;
    half_t* xl  = xh + (size_t)HEAD_ELEMS;
    half_t* whp = xl + (size_t)HEAD_ELEMS;             // 196608 halfs
    half_t* pO  = xh;                                  // alias

    // split-K 4 needs 12.58M + 16.78M + 1.05M ≈ 30.4 MB of ws (verified fits in r9)
    const int nsplit = (ws_size >= 31000000u) ? 4 : 2;
    float* mst = (float*)((char*)d_ws + 12582912 + (size_t)nsplit * HEAD_ELEMS * 2);
    float* lst = mst + (size_t)nsplit * NQROWS;

    prep<<<2048, 256, 0, stream>>>(x, Wq, xh, xl, whp);
    qkv_proj<<<dim3(NROW / 64, NE / 64), 256, 0, stream>>>(xh, xl, whp, bq, qh, kh, vt);
    attn<<<dim3(SS / 64, BH, nsplit), 128, 0, stream>>>(qh, kh, vt, pO, mst, lst);
    merge<<<1024, 256, 0, stream>>>(pO, mst, lst, out, nsplit);
}